// Round 5
// baseline (371.661 us; speedup 1.0000x reference)
//
#include <hip/hip_runtime.h>
#include <hip/hip_cooperative_groups.h>

namespace cg = cooperative_groups;

#define NTOK 8192
#define NCH  256
#define TT   64
#define XTP  264   // stride (u16) for [tok][ch] tiles
#define EKP  72    // stride (u16) for [ch][tok] tiles
#define TAP  70    // stride (u16) for transpose staging [ch][tok]

typedef unsigned short u16;
typedef __attribute__((ext_vector_type(8))) short bf16x8;
typedef __attribute__((ext_vector_type(4))) float f32x4;
typedef __attribute__((ext_vector_type(8))) unsigned short u16x8;
typedef __attribute__((ext_vector_type(4))) unsigned short u16x4;

__device__ __forceinline__ float b2f(u16 h){
  union{unsigned u; float f;} x; x.u = ((unsigned)h) << 16; return x.f;
}
__device__ __forceinline__ u16 f2b(float f){
  union{float f; unsigned u;} x; x.f = f;
  unsigned u = x.u;
  return (u16)((u + 0x7FFFu + ((u >> 16) & 1u)) >> 16);   // RNE
}
__device__ __forceinline__ f32x4 mfma16(bf16x8 a, bf16x8 b, f32x4 c){
  return __builtin_amdgcn_mfma_f32_16x16x32_bf16(a, b, c, 0, 0, 0);
}
// Load 8 W fragments (full K=256 sweep) for one output-channel row.
__device__ __forceinline__ void load_wfrags(const u16* __restrict__ Wb, int row,
                                            int quad, bf16x8* wf){
  const u16* p = Wb + (size_t)row * NCH + quad * 8;
  #pragma unroll
  for (int k = 0; k < 8; ++k) wf[k] = *(const bf16x8*)(p + k * 32);
}

// ---------------------------------------------------------------------------
// k_fused (cooperative, 256 blocks x 512 threads — co-residency guaranteed):
//   blocks 0..63 convert W (hidden behind tile-0 staging)
//   phase 1 (2 tiles/block): x load+transpose -> xT scratch; K/V GEMMs
//     (D[tok][och]); exp; ctx partials accumulated fp32 over both tiles
//   grid.sync -> 66 blocks reduce partials -> ctxT, 1/denom -> grid.sync
//   phase 2 (2 tiles/block): restage from xT; Q GEMM; softmax; att; Wr; out
// ---------------------------------------------------------------------------
__global__ __launch_bounds__(512, 4)
void k_fused(const float* __restrict__ x,
             const float* __restrict__ Wk, const float* __restrict__ Wq,
             const float* __restrict__ Wv, const float* __restrict__ Wr,
             const float* __restrict__ bk, const float* __restrict__ bq,
             const float* __restrict__ bv, const float* __restrict__ br,
             u16* __restrict__ wbf, u16* __restrict__ xT,
             u16* __restrict__ ctxPart, float* __restrict__ denomPart,
             u16* __restrict__ ctxT, float* __restrict__ rdenomF,
             float* __restrict__ out)
{
  __shared__ u16 reg1[NCH * EKP];   // xs [64][XTP] <-> vt [256][EKP]
  __shared__ u16 reg2[NCH * EKP];   // tA [256][TAP] -> ekb [256][EKP] -> qs [64][XTP]

  cg::grid_group grid = cg::this_grid();

  const int t = threadIdx.x;
  const int bid = blockIdx.x;
  const int b = bid >> 6;            // 4 batches x 64 blocks
  const int g0 = (bid & 63) * 2;     // first of two token-groups
  const int w = t >> 6, lane = t & 63;
  const int l15 = lane & 15, quad = lane >> 4;
  const int tok_t = t & 63, chb = (t >> 6) * 32;

  // ---- inline weight conversion (blocks 0..63; no LDS) ----
  if (bid < 64) {
    const int mat = bid >> 4;
    const float* src = (mat == 0) ? Wk : (mat == 1) ? Wq : (mat == 2) ? Wv : Wr;
    u16* dst = wbf + mat * 65536;
    const int base = (bid & 15) * 4096 + t * 8;
    #pragma unroll
    for (int i = 0; i < 2; ++i) {
      float4 v = *(const float4*)(src + base + i * 4);
      u16x4 pk; pk[0]=f2b(v.x); pk[1]=f2b(v.y); pk[2]=f2b(v.z); pk[3]=f2b(v.w);
      *(u16x4*)(dst + base + i * 4) = pk;
    }
    __threadfence();
  }

  // ---- stage + transpose tile 0 (pre-sync; hides W conversion) ----
  {
    const float* xb = x + ((size_t)b * NCH) * NTOK + g0 * TT;
    const int tq = (t & 15) * 4, ch0 = t >> 4;
    #pragma unroll
    for (int p = 0; p < 8; ++p) {
      int ch = p * 32 + ch0;
      float4 v = *(const float4*)(xb + (size_t)ch * NTOK + tq);
      u16x4 pk; pk[0]=f2b(v.x); pk[1]=f2b(v.y); pk[2]=f2b(v.z); pk[3]=f2b(v.w);
      *(u16x4*)&reg2[ch * TAP + tq] = pk;
    }
  }
  __syncthreads();
  #pragma unroll
  for (int i = 0; i < 4; ++i) {
    u16x8 v;
    #pragma unroll
    for (int j = 0; j < 8; ++j) v[j] = reg2[(chb + i * 8 + j) * TAP + tok_t];
    *(u16x8*)&reg1[tok_t * XTP + chb + i * 8] = v;
  }
  grid.sync();   // W ready everywhere; reg1 = xs(tile 0) block-locally

  const u16* Wkb = wbf;
  const u16* Wqb = wbf + 65536;
  const u16* Wvb = wbf + 2 * 65536;
  const u16* Wrb = wbf + 3 * 65536;

  f32x4 cacc[2][2];
  #pragma unroll
  for (int mi = 0; mi < 2; ++mi)
    #pragma unroll
    for (int nj = 0; nj < 2; ++nj) cacc[mi][nj] = (f32x4)0.f;
  float dsum = 0.f;

  // ================= phase 1: K/V/ctx over 2 tiles =================
  for (int c = 0; c < 2; ++c) {
    if (c == 1) {
      // stage + transpose tile 1 (prior tile consumed at end-of-loop barrier)
      const float* xb = x + ((size_t)b * NCH) * NTOK + (g0 + 1) * TT;
      const int tq = (t & 15) * 4, ch0 = t >> 4;
      #pragma unroll
      for (int p = 0; p < 8; ++p) {
        int ch = p * 32 + ch0;
        float4 v = *(const float4*)(xb + (size_t)ch * NTOK + tq);
        u16x4 pk; pk[0]=f2b(v.x); pk[1]=f2b(v.y); pk[2]=f2b(v.z); pk[3]=f2b(v.w);
        *(u16x4*)&reg2[ch * TAP + tq] = pk;
      }
      __syncthreads();
      #pragma unroll
      for (int i = 0; i < 4; ++i) {
        u16x8 v;
        #pragma unroll
        for (int j = 0; j < 8; ++j) v[j] = reg2[(chb + i * 8 + j) * TAP + tok_t];
        *(u16x8*)&reg1[tok_t * XTP + chb + i * 8] = v;
      }
      __syncthreads();
    }

    bf16x8 wfA[8], wfB[8];
    load_wfrags(Wkb, w * 32 + l15, quad, wfA);   // in flight over xT copy

    // coalesced bf16 tile copy-out to xT scratch (re-read in phase 2)
    {
      u16* dst = xT + ((size_t)(bid * 2 + c)) * 16384;
      #pragma unroll
      for (int i = 0; i < 4; ++i) {
        int f = i * 4096 + t * 8;
        *(u16x8*)(dst + f) = *(const u16x8*)&reg1[(f >> 8) * XTP + (f & 255)];
      }
    }

    const u16* abase = &reg1[l15 * XTP + quad * 8];
    f32x4 acc0[4], acc1[4];

    // K GEMM, D[tok][och], nj=0 (och = w*32 + l15)
    load_wfrags(Wkb, w * 32 + 16 + l15, quad, wfB);
    #pragma unroll
    for (int mi = 0; mi < 4; ++mi) acc0[mi] = (f32x4)0.f;
    #pragma unroll
    for (int k = 0; k < 8; ++k) {
      #pragma unroll
      for (int mi = 0; mi < 4; ++mi) {
        bf16x8 a = *(const bf16x8*)(abase + mi * 16 * XTP + k * 32);
        acc0[mi] = mfma16(a, wfA[k], acc0[mi]);
      }
    }
    {
      float bb = bk[w * 32 + l15];
      #pragma unroll
      for (int mi = 0; mi < 4; ++mi) {
        u16x4 pk;
        #pragma unroll
        for (int r = 0; r < 4; ++r) pk[r] = f2b(__expf(acc0[mi][r] + bb));
        *(u16x4*)&reg2[(w * 32 + l15) * EKP + mi * 16 + quad * 4] = pk;
      }
    }
    // K GEMM, nj=1
    load_wfrags(Wvb, w * 32 + l15, quad, wfA);
    #pragma unroll
    for (int mi = 0; mi < 4; ++mi) acc0[mi] = (f32x4)0.f;
    #pragma unroll
    for (int k = 0; k < 8; ++k) {
      #pragma unroll
      for (int mi = 0; mi < 4; ++mi) {
        bf16x8 a = *(const bf16x8*)(abase + mi * 16 * XTP + k * 32);
        acc0[mi] = mfma16(a, wfB[k], acc0[mi]);
      }
    }
    {
      float bb = bk[w * 32 + 16 + l15];
      #pragma unroll
      for (int mi = 0; mi < 4; ++mi) {
        u16x4 pk;
        #pragma unroll
        for (int r = 0; r < 4; ++r) pk[r] = f2b(__expf(acc0[mi][r] + bb));
        *(u16x4*)&reg2[(w * 32 + 16 + l15) * EKP + mi * 16 + quad * 4] = pk;
      }
    }
    // V GEMM, both nj at once
    load_wfrags(Wvb, w * 32 + 16 + l15, quad, wfB);
    #pragma unroll
    for (int mi = 0; mi < 4; ++mi) { acc0[mi] = (f32x4)0.f; acc1[mi] = (f32x4)0.f; }
    #pragma unroll
    for (int k = 0; k < 8; ++k) {
      #pragma unroll
      for (int mi = 0; mi < 4; ++mi) {
        bf16x8 a = *(const bf16x8*)(abase + mi * 16 * XTP + k * 32);
        acc0[mi] = mfma16(a, wfA[k], acc0[mi]);
        acc1[mi] = mfma16(a, wfB[k], acc1[mi]);
      }
    }
    __syncthreads();   // all waves done reading xs; reg1 becomes vt
    {
      float b0 = bv[w * 32 + l15], b1 = bv[w * 32 + 16 + l15];
      #pragma unroll
      for (int mi = 0; mi < 4; ++mi) {
        u16x4 p0, p1;
        #pragma unroll
        for (int r = 0; r < 4; ++r) { p0[r] = f2b(acc0[mi][r] + b0); p1[r] = f2b(acc1[mi][r] + b1); }
        *(u16x4*)&reg1[(w * 32 + l15) * EKP + mi * 16 + quad * 4] = p0;
        *(u16x4*)&reg1[(w * 32 + 16 + l15) * EKP + mi * 16 + quad * 4] = p1;
      }
    }
    // ctx GEMM (own-wave slabs; within-wave LDS ordering suffices)
    #pragma unroll
    for (int kc = 0; kc < 2; ++kc) {
      bf16x8 ae[2], bvv[2];
      #pragma unroll
      for (int mi = 0; mi < 2; ++mi)
        ae[mi] = *(const bf16x8*)&reg2[(w * 32 + mi * 16 + l15) * EKP + kc * 32 + quad * 8];
      #pragma unroll
      for (int nj = 0; nj < 2; ++nj)
        bvv[nj] = *(const bf16x8*)&reg1[(w * 32 + nj * 16 + l15) * EKP + kc * 32 + quad * 8];
      #pragma unroll
      for (int mi = 0; mi < 2; ++mi)
        #pragma unroll
        for (int nj = 0; nj < 2; ++nj)
          cacc[mi][nj] = mfma16(ae[mi], bvv[nj], cacc[mi][nj]);
    }
    // denominator: threads 0..255 sum ekb row t (cross-wave rows OK: all ek
    // writes precede the pre-vt barrier)
    if (t < 256) {
      #pragma unroll
      for (int s = 0; s < TT; s += 8) {
        u16x8 v = *(const u16x8*)&reg2[t * EKP + s];
        #pragma unroll
        for (int j = 0; j < 8; ++j) dsum += b2f(v[j]);
      }
    }
    __syncthreads();   // end of tile: reg1/reg2 free for next iteration
  }

  // ---- store partials (fp32-accumulated over both tiles, bf16 stored) ----
  {
    u16* cp = ctxPart + ((size_t)bid << 13);
    #pragma unroll
    for (int mi = 0; mi < 2; ++mi)
      #pragma unroll
      for (int nj = 0; nj < 2; ++nj)
        #pragma unroll
        for (int r = 0; r < 4; ++r) {
          int e = ((w * 32 + mi * 16 + quad * 4 + r) << 5) + nj * 16 + l15;
          cp[e] = f2b(cacc[mi][nj][r]);
        }
    if (t < 256)
      denomPart[(size_t)bid * 256 + t] = dsum;
  }
  __threadfence();
  grid.sync();

  // ================= reduction: 66 blocks cover 33792 items =================
  if (bid < 66) {
    int i = bid * 512 + t;
    if (i < 32768) {
      int bb_ = i >> 13, e = i & 8191;
      const u16* p = ctxPart + ((size_t)(bb_ * 64) << 13) + e;
      float s = 0.f;
      for (int gg = 0; gg < 64; ++gg) s += b2f(p[(size_t)gg << 13]);
      int hh = e >> 10, kk = (e >> 5) & 31, vch = e & 31;
      ctxT[(((bb_ * 8 + hh) * 32 + vch) << 5) + kk] = f2b(s);
    } else if (i < 33792) {
      int j = i - 32768, bb_ = j >> 8, ch = j & 255;
      const float* p = denomPart + (size_t)(bb_ * 64) * 256 + ch;
      float s = 0.f;
      for (int gg = 0; gg < 64; ++gg) s += p[(size_t)gg << 8];
      rdenomF[j] = 1.0f / s;
    }
    __threadfence();
  }
  grid.sync();

  // ================= phase 2: Q/att/Wr/out over 2 tiles =================
  for (int c = 0; c < 2; ++c) {
    const int s0 = (g0 + c) * TT;

    // restage xs from xT scratch (coalesced 16B)
    {
      const u16* src = xT + ((size_t)(bid * 2 + c)) * 16384;
      #pragma unroll
      for (int i = 0; i < 4; ++i) {
        int f = i * 4096 + t * 8;
        *(u16x8*)&reg1[(f >> 8) * XTP + (f & 255)] = *(const u16x8*)(src + f);
      }
    }
    bf16x8 wfA[8], wfB[8];
    load_wfrags(Wqb, w * 32 + l15, quad, wfA);
    load_wfrags(Wqb, w * 32 + 16 + l15, quad, wfB);
    __syncthreads();

    // Q GEMM, D[och][tok]; both mi passes
    f32x4 qa[2][4];
    #pragma unroll
    for (int nj = 0; nj < 4; ++nj) { qa[0][nj] = (f32x4)0.f; qa[1][nj] = (f32x4)0.f; }
    #pragma unroll
    for (int k = 0; k < 8; ++k) {
      #pragma unroll
      for (int nj = 0; nj < 4; ++nj) {
        bf16x8 bx = *(const bf16x8*)&reg1[(nj * 16 + l15) * XTP + k * 32 + quad * 8];
        qa[0][nj] = mfma16(wfA[k], bx, qa[0][nj]);
        qa[1][nj] = mfma16(wfB[k], bx, qa[1][nj]);
      }
    }
    // bias + exp
    #pragma unroll
    for (int mi = 0; mi < 2; ++mi) {
      float4 bb = *(const float4*)(bq + w * 32 + mi * 16 + quad * 4);
      #pragma unroll
      for (int nj = 0; nj < 4; ++nj) {
        qa[mi][nj][0] = __expf(qa[mi][nj][0] + bb.x);
        qa[mi][nj][1] = __expf(qa[mi][nj][1] + bb.y);
        qa[mi][nj][2] = __expf(qa[mi][nj][2] + bb.z);
        qa[mi][nj][3] = __expf(qa[mi][nj][3] + bb.w);
      }
    }
    // per-(head, token) softmax: in-lane + quad butterfly
    float inv[4];
    #pragma unroll
    for (int nj = 0; nj < 4; ++nj) {
      float s = 0.f;
      #pragma unroll
      for (int mi = 0; mi < 2; ++mi)
        #pragma unroll
        for (int r = 0; r < 4; ++r) s += qa[mi][nj][r];
      s += __shfl_xor(s, 16);
      s += __shfl_xor(s, 32);
      inv[nj] = 1.0f / s;
    }
    // qn -> qs [tok][ch] (reg2)
    #pragma unroll
    for (int mi = 0; mi < 2; ++mi) {
      float4 rd = *(const float4*)(rdenomF + b * 256 + w * 32 + mi * 16 + quad * 4);
      #pragma unroll
      for (int nj = 0; nj < 4; ++nj) {
        u16x4 pk;
        pk[0] = f2b(qa[mi][nj][0] * inv[nj] * rd.x);
        pk[1] = f2b(qa[mi][nj][1] * inv[nj] * rd.y);
        pk[2] = f2b(qa[mi][nj][2] * inv[nj] * rd.z);
        pk[3] = f2b(qa[mi][nj][3] * inv[nj] * rd.w);
        *(u16x4*)&reg2[(nj * 16 + l15) * XTP + w * 32 + mi * 16 + quad * 4] = pk;
      }
    }
    __syncthreads();

    // att GEMM: wave w -> head w; A = ctxT (global), B = qs
    f32x4 aacc[2][4];
    {
      bf16x8 ac[2];
      #pragma unroll
      for (int mi = 0; mi < 2; ++mi)
        ac[mi] = *(const bf16x8*)(ctxT + (((size_t)(b * 8 + w) * 32 + mi * 16 + l15) << 5) + quad * 8);
      #pragma unroll
      for (int nj = 0; nj < 4; ++nj) {
        bf16x8 bqf = *(const bf16x8*)&reg2[(nj * 16 + l15) * XTP + w * 32 + quad * 8];
        #pragma unroll
        for (int mi = 0; mi < 2; ++mi)
          aacc[mi][nj] = mfma16(ac[mi], bqf, (f32x4)0.f);
      }
    }
    load_wfrags(Wrb, w * 32 + l15, quad, wfA);
    #pragma unroll
    for (int mi = 0; mi < 2; ++mi)
      #pragma unroll
      for (int nj = 0; nj < 4; ++nj) {
        u16x4 pk;
        pk[0] = f2b(aacc[mi][nj][0]); pk[1] = f2b(aacc[mi][nj][1]);
        pk[2] = f2b(aacc[mi][nj][2]); pk[3] = f2b(aacc[mi][nj][3]);
        *(u16x4*)&reg2[(nj * 16 + l15) * XTP + w * 32 + mi * 16 + quad * 4] = pk;
      }
    __syncthreads();

    // Wr GEMM, D[och][tok]
    load_wfrags(Wrb, w * 32 + 16 + l15, quad, wfB);
    #pragma unroll
    for (int nj = 0; nj < 4; ++nj) { qa[0][nj] = (f32x4)0.f; qa[1][nj] = (f32x4)0.f; }
    #pragma unroll
    for (int k = 0; k < 8; ++k) {
      #pragma unroll
      for (int nj = 0; nj < 4; ++nj) {
        bf16x8 bx = *(const bf16x8*)&reg2[(nj * 16 + l15) * XTP + k * 32 + quad * 8];
        qa[0][nj] = mfma16(wfA[k], bx, qa[0][nj]);
        qa[1][nj] = mfma16(wfB[k], bx, qa[1][nj]);
      }
    }
    // bias + residual + coalesced store
    #pragma unroll
    for (int mi = 0; mi < 2; ++mi) {
      float4 bb = *(const float4*)(br + w * 32 + mi * 16 + quad * 4);
      #pragma unroll
      for (int nj = 0; nj < 4; ++nj) {
        int tok = nj * 16 + l15;
        u16x4 rx = *(const u16x4*)&reg1[tok * XTP + w * 32 + mi * 16 + quad * 4];
        float4 o;
        o.x = qa[mi][nj][0] + bb.x + b2f(rx[0]);
        o.y = qa[mi][nj][1] + bb.y + b2f(rx[1]);
        o.z = qa[mi][nj][2] + bb.z + b2f(rx[2]);
        o.w = qa[mi][nj][3] + bb.w + b2f(rx[3]);
        *(float4*)(out + (((size_t)(b * NTOK + s0 + tok)) << 8) + w * 32 + mi * 16 + quad * 4) = o;
      }
    }
    __syncthreads();   // before next c overwrites reg1/reg2
  }
}

extern "C" void kernel_launch(void* const* d_in, const int* in_sizes, int n_in,
                              void* d_out, int out_size, void* d_ws, size_t ws_size,
                              hipStream_t stream) {
  const float* x  = (const float*)d_in[0];
  const float* Wk = (const float*)d_in[1];
  const float* bk = (const float*)d_in[2];
  const float* Wq = (const float*)d_in[3];
  const float* bq = (const float*)d_in[4];
  const float* Wv = (const float*)d_in[5];
  const float* bv = (const float*)d_in[6];
  const float* Wr = (const float*)d_in[7];
  const float* br = (const float*)d_in[8];
  float* out = (float*)d_out;

  // ws layout (21.8 MB total)
  char* wsb = (char*)d_ws;
  u16*   ctxPart   = (u16*)wsb;                  // 256*8192 u16   = 4 MB
  float* denomPart = (float*)(wsb + 4194304);    // 256*256 f32    = 256 KB
  u16*   ctxT      = (u16*)(wsb + 4456448);      // 32768 u16      = 64 KB
  float* rdenomF   = (float*)(wsb + 4521984);    // 1024 f32       = 4 KB
  u16*   wbf       = (u16*)(wsb + 4526080);      // 4*65536 u16    = 512 KB
  u16*   xT        = (u16*)(wsb + 5050368);      // 512*16384 u16  = 16 MB

  void* args[] = {(void*)&x, (void*)&Wk, (void*)&Wq, (void*)&Wv, (void*)&Wr,
                  (void*)&bk, (void*)&bq, (void*)&bv, (void*)&br,
                  (void*)&wbf, (void*)&xT, (void*)&ctxPart, (void*)&denomPart,
                  (void*)&ctxT, (void*)&rdenomF, (void*)&out};
  hipLaunchCooperativeKernel((void*)k_fused, dim3(256), dim3(512), args, 0, stream);
}

// Round 6
// 157.673 us; speedup vs baseline: 2.3572x; 2.3572x over previous
//
#include <hip/hip_runtime.h>

#define NTOK 8192
#define NCH  256
#define TT   64
#define XTP  264   // stride (u16) for [tok][ch] tiles
#define EKP  72    // stride (u16) for [ch][tok] tiles
#define TAP  70    // stride (u16) for transpose staging [ch][tok]

typedef unsigned short u16;
typedef __attribute__((ext_vector_type(8))) short bf16x8;
typedef __attribute__((ext_vector_type(4))) float f32x4;
typedef __attribute__((ext_vector_type(8))) unsigned short u16x8;
typedef __attribute__((ext_vector_type(4))) unsigned short u16x4;

__device__ __forceinline__ float b2f(u16 h){
  union{unsigned u; float f;} x; x.u = ((unsigned)h) << 16; return x.f;
}
__device__ __forceinline__ u16 f2b(float f){
  union{float f; unsigned u;} x; x.f = f;
  unsigned u = x.u;
  return (u16)((u + 0x7FFFu + ((u >> 16) & 1u)) >> 16);   // RNE
}
__device__ __forceinline__ f32x4 mfma16(bf16x8 a, bf16x8 b, f32x4 c){
  return __builtin_amdgcn_mfma_f32_16x16x32_bf16(a, b, c, 0, 0, 0);
}
__device__ __forceinline__ void load_wfrags(const u16* __restrict__ Wb, int row,
                                            int quad, bf16x8* wf){
  const u16* p = Wb + (size_t)row * NCH + quad * 8;
  #pragma unroll
  for (int k = 0; k < 8; ++k) wf[k] = *(const bf16x8*)(p + k * 32);
}

// ---------------------------------------------------------------------------
// k_prepw: convert Wk/Wq/Wv/Wr fp32 -> bf16 row-major
// ---------------------------------------------------------------------------
__global__ __launch_bounds__(256)
void k_prepw(const float* __restrict__ Wk, const float* __restrict__ Wq,
             const float* __restrict__ Wv, const float* __restrict__ Wr,
             u16* __restrict__ wbf)
{
  const int t = threadIdx.x, wb = blockIdx.x;
  const int mat = wb >> 4;
  const float* src = (mat == 0) ? Wk : (mat == 1) ? Wq : (mat == 2) ? Wv : Wr;
  u16* dst = wbf + mat * 65536;
  const int base = (wb & 15) * 4096 + t * 16;
  #pragma unroll
  for (int i = 0; i < 4; ++i) {
    float4 v = *(const float4*)(src + base + i * 4);
    u16x4 pk; pk[0]=f2b(v.x); pk[1]=f2b(v.y); pk[2]=f2b(v.z); pk[3]=f2b(v.w);
    *(u16x4*)(dst + base + i * 4) = pk;
  }
}

// ---------------------------------------------------------------------------
// k1: per 64-token tile: x load+transpose -> xT; K GEMM->exp; Q GEMM->softmax
// -> qhatT; V GEMM -> vt; ctx partials + denom -> ws. 512 thr, 2 blk/CU.
// ---------------------------------------------------------------------------
__global__ __launch_bounds__(512, 4)
void k1(const float* __restrict__ x, const u16* __restrict__ wbf,
        const float* __restrict__ bk, const float* __restrict__ bq,
        const float* __restrict__ bv,
        u16* __restrict__ xT, u16* __restrict__ qhatT,
        u16* __restrict__ ctxPart, float* __restrict__ denomPart)
{
  __shared__ u16 reg1[NCH * EKP];   // xs [64][XTP] -> vt [256][EKP]
  __shared__ u16 reg2[NCH * EKP];   // tA [256][TAP] -> ekb [256][EKP] -> qhat [64][XTP]

  const int t = threadIdx.x, bid = blockIdx.x;
  const int b = bid >> 7, g = bid & 127;
  const int w = t >> 6, lane = t & 63;
  const int l15 = lane & 15, quad = lane >> 4;
  const int tok_t = t & 63, chb = w * 32;
  const u16* Wkb = wbf;
  const u16* Wqb = wbf + 65536;
  const u16* Wvb = wbf + 2 * 65536;

  bf16x8 wfA[8], wfB[8];
  load_wfrags(Wkb, w * 32 + l15, quad, wfA);   // hide behind staging

  // ---- stage fp32 x tile -> bf16 tA [ch][tok] ----
  {
    const float* xb = x + ((size_t)b * NCH) * NTOK + g * TT;
    const int tq = (t & 15) * 4, ch0 = t >> 4;
    #pragma unroll
    for (int p = 0; p < 8; ++p) {
      int ch = p * 32 + ch0;
      float4 v = *(const float4*)(xb + (size_t)ch * NTOK + tq);
      u16x4 pk; pk[0]=f2b(v.x); pk[1]=f2b(v.y); pk[2]=f2b(v.z); pk[3]=f2b(v.w);
      *(u16x4*)&reg2[ch * TAP + tq] = pk;
    }
  }
  __syncthreads();
  // transpose -> xs (reg1 [tok][ch])
  #pragma unroll
  for (int i = 0; i < 4; ++i) {
    u16x8 v;
    #pragma unroll
    for (int j = 0; j < 8; ++j) v[j] = reg2[(chb + i * 8 + j) * TAP + tok_t];
    *(u16x8*)&reg1[tok_t * XTP + chb + i * 8] = v;
  }
  __syncthreads();
  // coalesced copy-out xs -> xT (re-used by k3 for residual + avoids re-read)
  {
    u16* dst = xT + ((size_t)(b * NTOK + g * TT)) * 256;
    #pragma unroll
    for (int i = 0; i < 4; ++i) {
      int f = i * 4096 + t * 8;
      *(u16x8*)(dst + f) = *(const u16x8*)&reg1[(f >> 8) * XTP + (f & 255)];
    }
  }

  const u16* abase = &reg1[l15 * XTP + quad * 8];
  f32x4 acc0[4], acc1[4];

  // ---- K GEMM, D[tok][och], nj=0 (och = w*32+l15) ----
  load_wfrags(Wkb, w * 32 + 16 + l15, quad, wfB);
  #pragma unroll
  for (int mi = 0; mi < 4; ++mi) acc0[mi] = (f32x4)0.f;
  #pragma unroll
  for (int k = 0; k < 8; ++k) {
    #pragma unroll
    for (int mi = 0; mi < 4; ++mi) {
      bf16x8 a = *(const bf16x8*)(abase + mi * 16 * XTP + k * 32);
      acc0[mi] = mfma16(a, wfA[k], acc0[mi]);
    }
  }
  {
    float bb = bk[w * 32 + l15];
    #pragma unroll
    for (int mi = 0; mi < 4; ++mi) {
      u16x4 pk;
      #pragma unroll
      for (int r = 0; r < 4; ++r) pk[r] = f2b(__expf(acc0[mi][r] + bb));
      *(u16x4*)&reg2[(w * 32 + l15) * EKP + mi * 16 + quad * 4] = pk;
    }
  }
  // ---- K GEMM, nj=1 ----
  load_wfrags(Wqb, w * 32 + l15, quad, wfA);   // prefetch Wq mi=0
  #pragma unroll
  for (int mi = 0; mi < 4; ++mi) acc0[mi] = (f32x4)0.f;
  #pragma unroll
  for (int k = 0; k < 8; ++k) {
    #pragma unroll
    for (int mi = 0; mi < 4; ++mi) {
      bf16x8 a = *(const bf16x8*)(abase + mi * 16 * XTP + k * 32);
      acc0[mi] = mfma16(a, wfB[k], acc0[mi]);
    }
  }
  {
    float bb = bk[w * 32 + 16 + l15];
    #pragma unroll
    for (int mi = 0; mi < 4; ++mi) {
      u16x4 pk;
      #pragma unroll
      for (int r = 0; r < 4; ++r) pk[r] = f2b(__expf(acc0[mi][r] + bb));
      *(u16x4*)&reg2[(w * 32 + 16 + l15) * EKP + mi * 16 + quad * 4] = pk;
    }
  }

  // ---- Q GEMM, D[och][tok] (wave w = head w); softmax; pack qhat ----
  u16x4 qp[2][4];
  {
    load_wfrags(Wqb, w * 32 + 16 + l15, quad, wfB);
    f32x4 qa[2][4];
    #pragma unroll
    for (int nj = 0; nj < 4; ++nj) { qa[0][nj] = (f32x4)0.f; qa[1][nj] = (f32x4)0.f; }
    #pragma unroll
    for (int k = 0; k < 8; ++k) {
      #pragma unroll
      for (int nj = 0; nj < 4; ++nj) {
        bf16x8 bx = *(const bf16x8*)&reg1[(nj * 16 + l15) * XTP + k * 32 + quad * 8];
        qa[0][nj] = mfma16(wfA[k], bx, qa[0][nj]);
        qa[1][nj] = mfma16(wfB[k], bx, qa[1][nj]);
      }
    }
    #pragma unroll
    for (int mi = 0; mi < 2; ++mi) {
      float4 bb = *(const float4*)(bq + w * 32 + mi * 16 + quad * 4);
      #pragma unroll
      for (int nj = 0; nj < 4; ++nj) {
        qa[mi][nj][0] = __expf(qa[mi][nj][0] + bb.x);
        qa[mi][nj][1] = __expf(qa[mi][nj][1] + bb.y);
        qa[mi][nj][2] = __expf(qa[mi][nj][2] + bb.z);
        qa[mi][nj][3] = __expf(qa[mi][nj][3] + bb.w);
      }
    }
    #pragma unroll
    for (int nj = 0; nj < 4; ++nj) {
      float s = 0.f;
      #pragma unroll
      for (int mi = 0; mi < 2; ++mi)
        #pragma unroll
        for (int r = 0; r < 4; ++r) s += qa[mi][nj][r];
      s += __shfl_xor(s, 16);
      s += __shfl_xor(s, 32);
      float inv = 1.0f / s;
      #pragma unroll
      for (int mi = 0; mi < 2; ++mi) {
        qp[mi][nj][0] = f2b(qa[mi][nj][0] * inv);
        qp[mi][nj][1] = f2b(qa[mi][nj][1] * inv);
        qp[mi][nj][2] = f2b(qa[mi][nj][2] * inv);
        qp[mi][nj][3] = f2b(qa[mi][nj][3] * inv);
      }
    }
  }

  // ---- V GEMM, both nj ----
  load_wfrags(Wvb, w * 32 + l15, quad, wfA);
  load_wfrags(Wvb, w * 32 + 16 + l15, quad, wfB);
  #pragma unroll
  for (int mi = 0; mi < 4; ++mi) { acc0[mi] = (f32x4)0.f; acc1[mi] = (f32x4)0.f; }
  #pragma unroll
  for (int k = 0; k < 8; ++k) {
    #pragma unroll
    for (int mi = 0; mi < 4; ++mi) {
      bf16x8 a = *(const bf16x8*)(abase + mi * 16 * XTP + k * 32);
      acc0[mi] = mfma16(a, wfA[k], acc0[mi]);
      acc1[mi] = mfma16(a, wfB[k], acc1[mi]);
    }
  }
  __syncthreads();   // xs reads done; reg1 becomes vt
  {
    float b0 = bv[w * 32 + l15], b1 = bv[w * 32 + 16 + l15];
    #pragma unroll
    for (int mi = 0; mi < 4; ++mi) {
      u16x4 p0, p1;
      #pragma unroll
      for (int r = 0; r < 4; ++r) { p0[r] = f2b(acc0[mi][r] + b0); p1[r] = f2b(acc1[mi][r] + b1); }
      *(u16x4*)&reg1[(w * 32 + l15) * EKP + mi * 16 + quad * 4] = p0;
      *(u16x4*)&reg1[(w * 32 + 16 + l15) * EKP + mi * 16 + quad * 4] = p1;
    }
  }

  // ---- ctx GEMM (own-wave head; within-wave LDS ordering) + denom ----
  f32x4 cacc[2][2];
  #pragma unroll
  for (int mi = 0; mi < 2; ++mi)
    #pragma unroll
    for (int nj = 0; nj < 2; ++nj) cacc[mi][nj] = (f32x4)0.f;
  #pragma unroll
  for (int kc = 0; kc < 2; ++kc) {
    bf16x8 ae[2], bvv[2];
    #pragma unroll
    for (int mi = 0; mi < 2; ++mi)
      ae[mi] = *(const bf16x8*)&reg2[(w * 32 + mi * 16 + l15) * EKP + kc * 32 + quad * 8];
    #pragma unroll
    for (int nj = 0; nj < 2; ++nj)
      bvv[nj] = *(const bf16x8*)&reg1[(w * 32 + nj * 16 + l15) * EKP + kc * 32 + quad * 8];
    #pragma unroll
    for (int mi = 0; mi < 2; ++mi)
      #pragma unroll
      for (int nj = 0; nj < 2; ++nj)
        cacc[mi][nj] = mfma16(ae[mi], bvv[nj], cacc[mi][nj]);
  }
  float dsum = 0.f;
  if (t < 256) {
    #pragma unroll
    for (int s = 0; s < TT; s += 8) {
      u16x8 v = *(const u16x8*)&reg2[t * EKP + s];
      #pragma unroll
      for (int j = 0; j < 8; ++j) dsum += b2f(v[j]);
    }
  }
  // store partials
  {
    u16* cp = ctxPart + ((size_t)bid << 13);
    #pragma unroll
    for (int mi = 0; mi < 2; ++mi)
      #pragma unroll
      for (int nj = 0; nj < 2; ++nj)
        #pragma unroll
        for (int r = 0; r < 4; ++r) {
          int e = ((w * 32 + mi * 16 + quad * 4 + r) << 5) + nj * 16 + l15;
          cp[e] = f2b(cacc[mi][nj][r]);
        }
    if (t < 256)
      denomPart[(size_t)bid * 256 + t] = dsum;
  }

  // ---- qhat -> reg2 [tok][ch] -> coalesced copy-out ----
  __syncthreads();   // all ekb reads (ctx + denom) done
  #pragma unroll
  for (int mi = 0; mi < 2; ++mi)
    #pragma unroll
    for (int nj = 0; nj < 4; ++nj)
      *(u16x4*)&reg2[(nj * 16 + l15) * XTP + w * 32 + mi * 16 + quad * 4] = qp[mi][nj];
  __syncthreads();
  {
    u16* dst = qhatT + ((size_t)(b * NTOK + g * TT)) * 256;
    #pragma unroll
    for (int i = 0; i < 4; ++i) {
      int f = i * 4096 + t * 8;
      *(u16x8*)(dst + f) = *(const u16x8*)&reg2[(f >> 8) * XTP + (f & 255)];
    }
  }
}

// ---------------------------------------------------------------------------
// k_red: sum 128 partials per batch -> ctxT bf16 [b][h][vch][kk] (unscaled)
// and rdenomF = 1/denom
// ---------------------------------------------------------------------------
__global__ __launch_bounds__(256)
void k_red(const u16* __restrict__ ctxPart, const float* __restrict__ denomPart,
           u16* __restrict__ ctxT, float* __restrict__ rdenomF)
{
  int i = blockIdx.x * 256 + threadIdx.x;
  if (i < 32768) {
    int b = i >> 13, e = i & 8191;
    const u16* p = ctxPart + ((size_t)(b * 128) << 13) + e;
    float s = 0.f;
    for (int g = 0; g < 128; ++g) s += b2f(p[(size_t)g << 13]);
    int hh = e >> 10, kk = (e >> 5) & 31, vch = e & 31;
    ctxT[(((b * 8 + hh) * 32 + vch) << 5) + kk] = f2b(s);
  } else if (i < 33792) {
    int j = i - 32768, b = j >> 8, ch = j & 255;
    const float* p = denomPart + (size_t)(b * 128) * 256 + ch;
    float s = 0.f;
    for (int g = 0; g < 128; ++g) s += p[(size_t)g << 8];
    rdenomF[j] = 1.0f / s;
  }
}

// ---------------------------------------------------------------------------
// k3: per 64-token tile: att GEMM (A = ctxT * rdenom, B = qhat tile) -> Wr
// GEMM -> bias + residual (xT) -> out. 512 thr, 2 blk/CU.
// ---------------------------------------------------------------------------
__global__ __launch_bounds__(512, 4)
void k3(const u16* __restrict__ xT, const u16* __restrict__ qhatT,
        const u16* __restrict__ wbf, const float* __restrict__ br,
        const u16* __restrict__ ctxT, const float* __restrict__ rdenomF,
        float* __restrict__ out)
{
  __shared__ u16 reg1[TT * XTP];   // x residual tile [tok][ch]
  __shared__ u16 reg2[TT * XTP];   // qhat tile -> att (wave-exclusive cols)

  const int t = threadIdx.x, bid = blockIdx.x;
  const int b = bid >> 7, g = bid & 127;
  const int s0 = g * TT;
  const int w = t >> 6, lane = t & 63;
  const int l15 = lane & 15, quad = lane >> 4;
  const u16* Wrb = wbf + 3 * 65536;

  bf16x8 wrA[8], wrB[8];
  load_wfrags(Wrb, w * 32 + l15, quad, wrA);
  load_wfrags(Wrb, w * 32 + 16 + l15, quad, wrB);

  // stage xs + qhat tiles (coalesced 16B)
  {
    const u16* sx = xT    + ((size_t)(b * NTOK + s0)) * 256;
    const u16* sq = qhatT + ((size_t)(b * NTOK + s0)) * 256;
    #pragma unroll
    for (int i = 0; i < 4; ++i) {
      int f = i * 4096 + t * 8;
      int off = (f >> 8) * XTP + (f & 255);
      *(u16x8*)&reg1[off] = *(const u16x8*)(sx + f);
      *(u16x8*)&reg2[off] = *(const u16x8*)(sq + f);
    }
  }
  __syncthreads();

  // ---- att GEMM: wave w -> head w; A = ctxT rows scaled by rdenom ----
  f32x4 aacc[2][4];
  {
    float rd[8];
    float4 r0 = *(const float4*)(rdenomF + b * 256 + w * 32 + quad * 8);
    float4 r1 = *(const float4*)(rdenomF + b * 256 + w * 32 + quad * 8 + 4);
    rd[0]=r0.x; rd[1]=r0.y; rd[2]=r0.z; rd[3]=r0.w;
    rd[4]=r1.x; rd[5]=r1.y; rd[6]=r1.z; rd[7]=r1.w;
    bf16x8 ac[2];
    #pragma unroll
    for (int mi = 0; mi < 2; ++mi) {
      u16x8 c = *(const u16x8*)(ctxT + (((size_t)(b * 8 + w) * 32 + mi * 16 + l15) << 5) + quad * 8);
      u16x8 sc;
      #pragma unroll
      for (int j = 0; j < 8; ++j) sc[j] = f2b(b2f(c[j]) * rd[j]);
      ac[mi] = *(bf16x8*)&sc;
    }
    #pragma unroll
    for (int nj = 0; nj < 4; ++nj) {
      bf16x8 bqf = *(const bf16x8*)&reg2[(nj * 16 + l15) * XTP + w * 32 + quad * 8];
      #pragma unroll
      for (int mi = 0; mi < 2; ++mi)
        aacc[mi][nj] = mfma16(ac[mi], bqf, (f32x4)0.f);
    }
  }
  // write att over qhat (wave-exclusive columns; in-wave read-before-write)
  #pragma unroll
  for (int mi = 0; mi < 2; ++mi)
    #pragma unroll
    for (int nj = 0; nj < 4; ++nj) {
      u16x4 pk;
      pk[0] = f2b(aacc[mi][nj][0]); pk[1] = f2b(aacc[mi][nj][1]);
      pk[2] = f2b(aacc[mi][nj][2]); pk[3] = f2b(aacc[mi][nj][3]);
      *(u16x4*)&reg2[(nj * 16 + l15) * XTP + w * 32 + mi * 16 + quad * 4] = pk;
    }
  __syncthreads();

  // ---- Wr GEMM, D[och][tok] ----
  f32x4 qa[2][4];
  #pragma unroll
  for (int nj = 0; nj < 4; ++nj) { qa[0][nj] = (f32x4)0.f; qa[1][nj] = (f32x4)0.f; }
  #pragma unroll
  for (int k = 0; k < 8; ++k) {
    #pragma unroll
    for (int nj = 0; nj < 4; ++nj) {
      bf16x8 bx = *(const bf16x8*)&reg2[(nj * 16 + l15) * XTP + k * 32 + quad * 8];
      qa[0][nj] = mfma16(wrA[k], bx, qa[0][nj]);
      qa[1][nj] = mfma16(wrB[k], bx, qa[1][nj]);
    }
  }
  // bias + residual + coalesced store
  #pragma unroll
  for (int mi = 0; mi < 2; ++mi) {
    float4 bb = *(const float4*)(br + w * 32 + mi * 16 + quad * 4);
    #pragma unroll
    for (int nj = 0; nj < 4; ++nj) {
      int tok = nj * 16 + l15;
      u16x4 rx = *(const u16x4*)&reg1[tok * XTP + w * 32 + mi * 16 + quad * 4];
      float4 o;
      o.x = qa[mi][nj][0] + bb.x + b2f(rx[0]);
      o.y = qa[mi][nj][1] + bb.y + b2f(rx[1]);
      o.z = qa[mi][nj][2] + bb.z + b2f(rx[2]);
      o.w = qa[mi][nj][3] + bb.w + b2f(rx[3]);
      *(float4*)(out + (((size_t)(b * NTOK + s0 + tok)) << 8) + w * 32 + mi * 16 + quad * 4) = o;
    }
  }
}

extern "C" void kernel_launch(void* const* d_in, const int* in_sizes, int n_in,
                              void* d_out, int out_size, void* d_ws, size_t ws_size,
                              hipStream_t stream) {
  const float* x  = (const float*)d_in[0];
  const float* Wk = (const float*)d_in[1];
  const float* bk = (const float*)d_in[2];
  const float* Wq = (const float*)d_in[3];
  const float* bq = (const float*)d_in[4];
  const float* Wv = (const float*)d_in[5];
  const float* bv = (const float*)d_in[6];
  const float* Wr = (const float*)d_in[7];
  const float* br = (const float*)d_in[8];
  float* out = (float*)d_out;

  // ws layout (~41.3 MB)
  char* wsb = (char*)d_ws;
  u16*   ctxPart   = (u16*)wsb;                  // 512*8192 u16   = 8 MB
  float* denomPart = (float*)(wsb + 8388608);    // 512*256 f32    = 512 KB
  u16*   ctxT      = (u16*)(wsb + 8912896);      // 32768 u16      = 64 KB
  float* rdenomF   = (float*)(wsb + 8978432);    // 1024 f32       = 4 KB
  u16*   wbf       = (u16*)(wsb + 8982528);      // 4*65536 u16    = 512 KB
  u16*   xT        = (u16*)(wsb + 9506816);      // 4*8192*256 u16 = 16 MB
  u16*   qhatT     = (u16*)(wsb + 26284032);     // 4*8192*256 u16 = 16 MB

  hipLaunchKernelGGL(k_prepw, dim3(64), dim3(256), 0, stream, Wk, Wq, Wv, Wr, wbf);
  hipLaunchKernelGGL(k1, dim3(512), dim3(512), 0, stream,
                     x, wbf, bk, bq, bv, xT, qhatT, ctxPart, denomPart);
  hipLaunchKernelGGL(k_red, dim3(132), dim3(256), 0, stream,
                     ctxPart, denomPart, ctxT, rdenomF);
  hipLaunchKernelGGL(k3, dim3(512), dim3(512), 0, stream,
                     xT, qhatT, wbf, br, ctxT, rdenomF, out);
}